// Round 8
// baseline (5709.493 us; speedup 1.0000x reference)
//
#include <hip/hip_runtime.h>

// Residual VQ: N=65536, D=256, K=1024, 4 codebooks.
// Inputs: bf16 (runtime-detected, f32 fallback): z [N][D], cb [4][K][D].
// Output: FLOAT32 concat: quant_sum [N][D] | inds [N][4] | loss [1].
//
// Round 8: numpy-float32 bitwise emulation on the round-7 skeleton (which is
// proven to execute; its f64-exact scoring showed Output1=992 => ref is f32).
//  - dot: sequential f32 fmaf chain d=0..255 (OpenBLAS sgemm order)
//  - r2/w2: numpy pairwise SIMD sum, AVX512 W=16: 128+128 split, 8x16-lane
//    accumulators, ((r0+r1)+(r2+r3))+((r4+r5)+(r6+r7)), butterfly 8,4,2,1
//  - dist = fl(fl(r2-2*dot)+w2), argmin first-index ties
//  - straight-through f32 dance; quant_sum = ((s1+s2)+s3)+s4 in registers
// Rules: no __shfl (shuffle rounds were silent no-ops), single instantiation,
// LDS-tree reductions, canary stamps 512.0f for decode.

#define N_TOK 65536
#define DIM   256
#define KCB   1024
#define NCBK  4

#define TM  32          // rows per block
#define TK  64          // codes per k-tile
#define DC  32          // d-chunk per W stage
#define RST 260         // f32 LDS stride, residual rows
#define WST 36          // f32 LDS stride, W rows

#define QS_F   ((size_t)N_TOK * DIM)             // 16777216 f32 elements
#define IDX_F  QS_F
#define IDXE_F (IDX_F + (size_t)N_TOK * NCBK)    // 17039360
#define LOSS_F IDXE_F                            // 17039360

// d_ws: float w2f[4096] @0 | double partials[2048] @16384 | int flags[2] @32768
#define WS_PART_OFF 16384
#define WS_FLAG_OFF 32768

typedef unsigned short u16;
typedef unsigned int   u32;

__device__ __forceinline__ float bf2f(u32 h) { return __uint_as_float(h << 16); }

__device__ __forceinline__ float getv(const void* base, int f32in, size_t elt) {
    if (f32in) return ((const float*)base)[elt];
    return bf2f(((const u16*)base)[elt]);
}

__device__ __forceinline__ void load8(const void* base, int f32in, size_t elt,
                                      float* f) {
    if (f32in) {
        const float* p = (const float*)base + elt;
        for (int e = 0; e < 8; ++e) f[e] = p[e];
    } else {
        uint4 q = *(const uint4*)((const u16*)base + elt);
        f[0] = bf2f(q.x & 0xffffu); f[1] = bf2f(q.x >> 16);
        f[2] = bf2f(q.y & 0xffffu); f[3] = bf2f(q.y >> 16);
        f[4] = bf2f(q.z & 0xffffu); f[5] = bf2f(q.z >> 16);
        f[6] = bf2f(q.w & 0xffffu); f[7] = bf2f(q.w >> 16);
    }
}

// canary: stamp f32 index region + loss with 512.0f (decodable no-op signal)
__global__ void canary_kernel(float* out) {
    int gid = blockIdx.x * 256 + threadIdx.x;
    size_t pos = IDX_F + (size_t)gid;
    if (pos < IDXE_F) out[pos] = 512.0f;
    if (gid == 0) out[LOSS_F] = 512.0f;
}

// dtype detect (bf16 vs f32), as round 7 (proven)
__global__ void detect_kernel(const u16* z16, const u16* cb16, int* flags) {
    __shared__ int s0[256], s1[256];
    int tid = threadIdx.x;
    u32 a = z16[tid],  ea = (a >> 7) & 0xffu;
    u32 b = cb16[tid], eb = (b >> 7) & 0xffu;
    s0[tid] = ((ea >= 90u && ea <= 140u) || ((a & 0x7fffu) == 0u)) ? 1 : 0;
    s1[tid] = ((eb >= 90u && eb <= 140u) || ((b & 0x7fffu) == 0u)) ? 1 : 0;
    __syncthreads();
    for (int st = 128; st > 0; st >>= 1) {
        if (tid < st) { s0[tid] += s0[tid + st]; s1[tid] += s1[tid + st]; }
        __syncthreads();
    }
    if (tid == 0) { flags[0] = (s0[0] < 218) ? 1 : 0;   // 1 => f32
                    flags[1] = (s1[0] < 218) ? 1 : 0; }
}

// numpy pairwise sum-of-squares, one 128 block, AVX512 W=16 order
__device__ __forceinline__ float np128_sq_g(const void* base, int f32in, size_t off) {
    float S[16];
    for (int l = 0; l < 16; ++l) {
        float A[8];
        for (int j = 0; j < 8; ++j) {
            float x = getv(base, f32in, off + 16 * j + l);
            A[j] = x * x;
        }
        S[l] = ((A[0] + A[1]) + (A[2] + A[3])) + ((A[4] + A[5]) + (A[6] + A[7]));
    }
    float B1[8], B2[4];
    for (int l = 0; l < 8; ++l) B1[l] = S[l] + S[l + 8];
    for (int l = 0; l < 4; ++l) B2[l] = B1[l] + B1[l + 4];
    return (B2[0] + B2[2]) + (B2[1] + B2[3]);
}

__device__ __forceinline__ float np128_sq_lds(const float* a) {
    float S[16];
    for (int l = 0; l < 16; ++l) {
        float A[8];
        for (int j = 0; j < 8; ++j) { float x = a[16 * j + l]; A[j] = x * x; }
        S[l] = ((A[0] + A[1]) + (A[2] + A[3])) + ((A[4] + A[5]) + (A[6] + A[7]));
    }
    float B1[8], B2[4];
    for (int l = 0; l < 8; ++l) B1[l] = S[l] + S[l + 8];
    for (int l = 0; l < 4; ++l) B2[l] = B1[l] + B1[l + 4];
    return (B2[0] + B2[2]) + (B2[1] + B2[3]);
}

__global__ void w2_kernel(const void* cbs, float* w2f, const int* flags) {
    int kf = blockIdx.x * 256 + threadIdx.x;      // 0..4095
    const int fc = flags[1];
    size_t base = (size_t)kf * DIM;
    float h0 = np128_sq_g(cbs, fc, base);
    float h1 = np128_sq_g(cbs, fc, base + 128);
    w2f[kf] = h0 + h1;                            // 256 = 128+128 split
}

__global__ __launch_bounds__(256)
void rq_kernel(const void* z, const void* cbs, const float* w2f,
               float* out, double* partials, const int* flags) {
    __shared__ float  Rld[TM * RST];        // 33280 B
    __shared__ float  Wld[TK * WST];        //  9216 B
    __shared__ float  candv[TM * 33];       //  4224 B
    __shared__ int    candi[TM * 33];       //  4224 B
    __shared__ float  r2s[TM];              //   128 B
    __shared__ int    bestk[TM];            //   128 B
    __shared__ double dred[256];            //  2048 B  => ~53 KB

    const int fz = flags[0], fc = flags[1];
    const int tid  = threadIdx.x;
    const int tx   = tid & 31;
    const int ty   = tid >> 5;
    const int row0 = blockIdx.x * TM;

    // stage residual (= z) into LDS as f32; zero quant accumulators
    float q[32];
    for (int e = 0; e < 32; ++e) q[e] = 0.f;

    for (int it = 0; it < 4; ++it) {
        int flat = it * 256 + tid;
        int r = flat >> 5, c8 = flat & 31;
        float f[8];
        load8(z, fz, (size_t)(row0 + r) * DIM + c8 * 8, f);
        int base = r * RST + c8 * 8;
        for (int e = 0; e < 8; ++e) Rld[base + e] = f[e];
    }
    double lsum = 0.0;

    for (int cb = 0; cb < NCBK; ++cb) {
        const size_t cbW = (size_t)cb * KCB * DIM;
        const float* w2c = w2f + cb * KCB;

        __syncthreads();                     // Rld settled
        if (tid < TM) {                      // r2 = np pairwise sum(r*r)
            const float* a = &Rld[tid * RST];
            r2s[tid] = np128_sq_lds(a) + np128_sq_lds(a + 128);
        }
        __syncthreads();

        float r2v[4];
        for (int i = 0; i < 4; ++i) r2v[i] = r2s[ty + 8 * i];

        float bval[4]; int bidx[4];
        for (int i = 0; i < 4; ++i) { bval[i] = __uint_as_float(0x7f7fffffu); bidx[i] = 0; }

        for (int kt = 0; kt < KCB / TK; ++kt) {
            float accf[8];                   // [row i][j], sequential-d chains
            for (int t = 0; t < 8; ++t) accf[t] = 0.f;

            for (int dc = 0; dc < DIM / DC; ++dc) {
                __syncthreads();             // prior Wld readers done
                {   // stage [64]x[32] W chunk, 8 elems/thread
                    int k = tid >> 2, dp = (tid & 3) * 8;
                    float f[8];
                    load8(cbs, fc, cbW + (size_t)(kt * TK + k) * DIM + dc * DC + dp, f);
                    int base = k * WST + dp;
                    for (int e = 0; e < 8; ++e) Wld[base + e] = f[e];
                }
                __syncthreads();

                for (int dd = 0; dd < DC / 4; ++dd) {
                    float av[4][4], bv[2][4];
                    for (int i = 0; i < 4; ++i) {
                        int ab = (ty + 8 * i) * RST + dc * DC + dd * 4;
                        for (int e = 0; e < 4; ++e) av[i][e] = Rld[ab + e];
                    }
                    for (int j = 0; j < 2; ++j) {
                        int bb = (tx + 32 * j) * WST + dd * 4;
                        for (int e = 0; e < 4; ++e) bv[j][e] = Wld[bb + e];
                    }
                    for (int i = 0; i < 4; ++i)
                        for (int j = 0; j < 2; ++j) {
                            float s = accf[i * 2 + j];
                            s = fmaf(av[i][0], bv[j][0], s);   // d ascending:
                            s = fmaf(av[i][1], bv[j][1], s);   // BLAS sgemm
                            s = fmaf(av[i][2], bv[j][2], s);   // sequential-k
                            s = fmaf(av[i][3], bv[j][3], s);   // FMA chain
                            accf[i * 2 + j] = s;
                        }
                }
            }
            // dist = fl(fl(r2 - 2*dot) + w2), f32; first-index ties
            for (int j = 0; j < 2; ++j) {
                int k = kt * TK + tx + 32 * j;
                float w2k = w2c[k];
                for (int i = 0; i < 4; ++i) {
                    float t2   = r2v[i] - 2.0f * accf[i * 2 + j];
                    float dist = t2 + w2k;
                    if (dist < bval[i] || (dist == bval[i] && k < bidx[i])) {
                        bval[i] = dist; bidx[i] = k;
                    }
                }
            }
        }
        // argmin across 32 lanes via LDS (no shuffles)
        __syncthreads();
        for (int i = 0; i < 4; ++i) {
            int r = ty + 8 * i;
            candv[r * 33 + tx] = bval[i];
            candi[r * 33 + tx] = bidx[i];
        }
        __syncthreads();
        if (tid < TM) {
            float best = candv[tid * 33];
            int   bi   = candi[tid * 33];
            for (int t = 1; t < 32; ++t) {
                float v = candv[tid * 33 + t];
                int  ix = candi[tid * 33 + t];
                if (v < best || (v == best && ix < bi)) { best = v; bi = ix; }
            }
            bestk[tid] = bi;
            size_t pos = IDX_F + (size_t)(row0 + tid) * NCBK + cb;
            if (pos < IDXE_F) out[pos] = (float)bi;
        }
        __syncthreads();
        // straight-through dance, elementwise f32 (np bit order):
        // t = zq - r; s = r + t; r' = r - s; q += s; loss += t^2
        for (int it = 0; it < 4; ++it) {
            int flat = it * 256 + tid;
            int r = flat >> 5, c8 = flat & 31;
            int kb = bestk[r];
            float f[8];
            load8(cbs, fc, cbW + (size_t)kb * DIM + c8 * 8, f);
            int base = r * RST + c8 * 8;
            for (int e = 0; e < 8; ++e) {
                float rv = Rld[base + e];
                float t  = f[e] - rv;
                float s  = rv + t;
                float rn = rv - s;
                Rld[base + e] = rn;
                q[it * 8 + e] = q[it * 8 + e] + s;
                lsum += (double)t * (double)t;
            }
        }
        __syncthreads();
    }

    // quant_sum writes from registers (f32)
    for (int it = 0; it < 4; ++it) {
        int flat = it * 256 + tid;
        int r = flat >> 5, c8 = flat & 31;
        size_t pos = (size_t)(row0 + r) * DIM + c8 * 8;
        if (pos + 8 <= QS_F) {
            for (int e = 0; e < 8; ++e) out[pos + e] = q[it * 8 + e];
        }
    }

    // loss: per-block f64 LDS tree -> partials[block]
    dred[tid] = lsum;
    __syncthreads();
    for (int s = 128; s > 0; s >>= 1) {
        if (tid < s) dred[tid] += dred[tid + s];
        __syncthreads();
    }
    if (tid == 0) partials[blockIdx.x] = dred[0];
}

__global__ void loss_final(const double* partials, float* out) {
    __shared__ double sred[256];
    int tid = threadIdx.x;
    double s = 0.0;
    for (int q = 0; q < 8; ++q) s += partials[tid + 256 * q];
    sred[tid] = s;
    __syncthreads();
    for (int st = 128; st > 0; st >>= 1) {
        if (tid < st) sred[tid] += sred[tid + st];
        __syncthreads();
    }
    if (tid == 0)
        out[LOSS_F] = (float)(2.0 * sred[0] / 16777216.0);  // 2*S/(N*D)
}

extern "C" void kernel_launch(void* const* d_in, const int* in_sizes, int n_in,
                              void* d_out, int out_size, void* d_ws, size_t ws_size,
                              hipStream_t stream) {
    (void)n_in; (void)out_size; (void)ws_size;
    const void* z;
    const void* cbs;
    if (in_sizes[0] == 16777216) { z = d_in[0]; cbs = d_in[1]; }
    else                         { z = d_in[1]; cbs = d_in[0]; }

    float*  out      = (float*)d_out;
    float*  w2f      = (float*)d_ws;
    double* partials = (double*)((char*)d_ws + WS_PART_OFF);
    int*    flags    = (int*)((char*)d_ws + WS_FLAG_OFF);

    canary_kernel<<<1024, 256, 0, stream>>>(out);
    detect_kernel<<<1, 256, 0, stream>>>((const u16*)z, (const u16*)cbs, flags);
    w2_kernel<<<16, 256, 0, stream>>>(cbs, w2f, flags);
    rq_kernel<<<N_TOK / TM, 256, 0, stream>>>(z, cbs, w2f, out, partials, flags);
    loss_final<<<1, 256, 0, stream>>>(partials, out);
}

// Round 9
// 2628.010 us; speedup vs baseline: 2.1726x; 2.1726x over previous
//
#include <hip/hip_runtime.h>

// Residual VQ: N=65536, D=256, K=1024, 4 codebooks.
// Inputs: bf16 (runtime-detected, f32 fallback): z [N][D], cb [4][K][D].
// Output: FLOAT32 concat: quant_sum [N][D] | inds [N][4] | loss [1].
//
// Round 9: perf pass on the bitwise-verified round-8 math (absmax 0.0).
//  - numpy-f32 bitwise scoring chain preserved EXACTLY: sequential fmaf dot
//    (d=0..255), AVX512-W16 pairwise r2/w2, dist = fl(fl(r2-2dot)+w2),
//    first-index ties, elementwise straight-through dance.
//  - NEW: 4 rows x 8 codes register tile (TK=256), Wld stride 34
//    (2-way bank aliasing = free vs old 36 => 8-way), b64-friendly.
//  - R8 counters: VALUBusy 28%, LDS_BANK_CONFLICT 5.15e8, 15% of 874us
//    f32-FMA floor. Predicted here: ~1.3-1.7ms, VALUBusy 65-80%.
// Rules: no __shfl, single instantiation, LDS-tree reductions, canary.

#define N_TOK 65536
#define DIM   256
#define KCB   1024
#define NCBK  4

#define TM  32          // rows per block
#define TK  256         // codes per k-tile
#define DC  32          // d-chunk per W stage
#define RST 260         // f32 LDS stride, residual rows (16B-aligned)
#define WST 34          // f32 LDS stride, W rows (==2 mod 32: conflict-free-ish)

#define QS_F   ((size_t)N_TOK * DIM)             // 16777216 f32 elements
#define IDX_F  QS_F
#define IDXE_F (IDX_F + (size_t)N_TOK * NCBK)    // 17039360
#define LOSS_F IDXE_F                            // 17039360

// d_ws: float w2f[4096] @0 | double partials[2048] @16384 | int flags[2] @32768
#define WS_PART_OFF 16384
#define WS_FLAG_OFF 32768

typedef unsigned short u16;
typedef unsigned int   u32;

__device__ __forceinline__ float bf2f(u32 h) { return __uint_as_float(h << 16); }

__device__ __forceinline__ float getv(const void* base, int f32in, size_t elt) {
    if (f32in) return ((const float*)base)[elt];
    return bf2f(((const u16*)base)[elt]);
}

__device__ __forceinline__ void load8(const void* base, int f32in, size_t elt,
                                      float* f) {
    if (f32in) {
        const float* p = (const float*)base + elt;
        #pragma unroll
        for (int e = 0; e < 8; ++e) f[e] = p[e];
    } else {
        uint4 q = *(const uint4*)((const u16*)base + elt);
        f[0] = bf2f(q.x & 0xffffu); f[1] = bf2f(q.x >> 16);
        f[2] = bf2f(q.y & 0xffffu); f[3] = bf2f(q.y >> 16);
        f[4] = bf2f(q.z & 0xffffu); f[5] = bf2f(q.z >> 16);
        f[6] = bf2f(q.w & 0xffffu); f[7] = bf2f(q.w >> 16);
    }
}

// canary: stamp f32 index region + loss with 512.0f (decodable no-op signal)
__global__ void canary_kernel(float* out) {
    int gid = blockIdx.x * 256 + threadIdx.x;
    size_t pos = IDX_F + (size_t)gid;
    if (pos < IDXE_F) out[pos] = 512.0f;
    if (gid == 0) out[LOSS_F] = 512.0f;
}

// dtype detect (bf16 vs f32), proven in rounds 7/8
__global__ void detect_kernel(const u16* z16, const u16* cb16, int* flags) {
    __shared__ int s0[256], s1[256];
    int tid = threadIdx.x;
    u32 a = z16[tid],  ea = (a >> 7) & 0xffu;
    u32 b = cb16[tid], eb = (b >> 7) & 0xffu;
    s0[tid] = ((ea >= 90u && ea <= 140u) || ((a & 0x7fffu) == 0u)) ? 1 : 0;
    s1[tid] = ((eb >= 90u && eb <= 140u) || ((b & 0x7fffu) == 0u)) ? 1 : 0;
    __syncthreads();
    for (int st = 128; st > 0; st >>= 1) {
        if (tid < st) { s0[tid] += s0[tid + st]; s1[tid] += s1[tid + st]; }
        __syncthreads();
    }
    if (tid == 0) { flags[0] = (s0[0] < 218) ? 1 : 0;   // 1 => f32
                    flags[1] = (s1[0] < 218) ? 1 : 0; }
}

// numpy pairwise sum-of-squares, one 128 block, AVX512 W=16 order
__device__ __forceinline__ float np128_sq_g(const void* base, int f32in, size_t off) {
    float S[16];
    #pragma unroll
    for (int l = 0; l < 16; ++l) {
        float A[8];
        #pragma unroll
        for (int j = 0; j < 8; ++j) {
            float x = getv(base, f32in, off + 16 * j + l);
            A[j] = x * x;
        }
        S[l] = ((A[0] + A[1]) + (A[2] + A[3])) + ((A[4] + A[5]) + (A[6] + A[7]));
    }
    float B1[8], B2[4];
    #pragma unroll
    for (int l = 0; l < 8; ++l) B1[l] = S[l] + S[l + 8];
    #pragma unroll
    for (int l = 0; l < 4; ++l) B2[l] = B1[l] + B1[l + 4];
    return (B2[0] + B2[2]) + (B2[1] + B2[3]);
}

__device__ __forceinline__ float np128_sq_lds(const float* a) {
    float S[16];
    #pragma unroll
    for (int l = 0; l < 16; ++l) {
        float A[8];
        #pragma unroll
        for (int j = 0; j < 8; ++j) { float x = a[16 * j + l]; A[j] = x * x; }
        S[l] = ((A[0] + A[1]) + (A[2] + A[3])) + ((A[4] + A[5]) + (A[6] + A[7]));
    }
    float B1[8], B2[4];
    #pragma unroll
    for (int l = 0; l < 8; ++l) B1[l] = S[l] + S[l + 8];
    #pragma unroll
    for (int l = 0; l < 4; ++l) B2[l] = B1[l] + B1[l + 4];
    return (B2[0] + B2[2]) + (B2[1] + B2[3]);
}

__global__ void w2_kernel(const void* cbs, float* w2f, const int* flags) {
    int kf = blockIdx.x * 256 + threadIdx.x;      // 0..4095
    const int fc = flags[1];
    size_t base = (size_t)kf * DIM;
    w2f[kf] = np128_sq_g(cbs, fc, base) + np128_sq_g(cbs, fc, base + 128);
}

__global__ __launch_bounds__(256, 2)
void rq_kernel(const void* z, const void* cbs, const float* w2f,
               float* out, double* partials, const int* flags) {
    __shared__ float  Rld[TM * RST];        // 33280 B
    __shared__ float  Wld[TK * WST];        // 34816 B
    __shared__ float  candv[TM * 33];       //  4224 B
    __shared__ int    candi[TM * 33];       //  4224 B
    __shared__ float  r2s[TM];              //   128 B
    __shared__ int    bestk[TM];            //   128 B
    __shared__ double dred[256];            //  2048 B  => 78848 B (2 blk/CU)

    const int fz = flags[0], fc = flags[1];
    const int tid  = threadIdx.x;
    const int tx   = tid & 31;              // code lane
    const int ty   = tid >> 5;              // row group 0..7
    const int row0 = blockIdx.x * TM;

    float q[32];
    #pragma unroll
    for (int e = 0; e < 32; ++e) q[e] = 0.f;

    for (int it = 0; it < 4; ++it) {
        int flat = it * 256 + tid;
        int r = flat >> 5, c8 = flat & 31;
        float f[8];
        load8(z, fz, (size_t)(row0 + r) * DIM + c8 * 8, f);
        int base = r * RST + c8 * 8;
        #pragma unroll
        for (int e = 0; e < 8; ++e) Rld[base + e] = f[e];
    }
    double lsum = 0.0;

    for (int cb = 0; cb < NCBK; ++cb) {
        const size_t cbW = (size_t)cb * KCB * DIM;
        const float* w2c = w2f + cb * KCB;

        __syncthreads();                     // Rld settled
        if (tid < TM) {                      // r2 = np pairwise sum(r*r)
            const float* a = &Rld[tid * RST];
            r2s[tid] = np128_sq_lds(a) + np128_sq_lds(a + 128);
        }
        __syncthreads();

        float r2v[4];
        #pragma unroll
        for (int i = 0; i < 4; ++i) r2v[i] = r2s[ty + 8 * i];

        float bval[4]; int bidx[4];
        #pragma unroll
        for (int i = 0; i < 4; ++i) { bval[i] = __uint_as_float(0x7f7fffffu); bidx[i] = 0; }

        for (int kt = 0; kt < KCB / TK; ++kt) {          // 4 tiles of 256 codes
            float acc[4][8];                 // sequential-d f32 chains
            #pragma unroll
            for (int i = 0; i < 4; ++i)
                #pragma unroll
                for (int j = 0; j < 8; ++j) acc[i][j] = 0.f;

            for (int dc = 0; dc < DIM / DC; ++dc) {
                __syncthreads();             // prior Wld readers done
                #pragma unroll
                for (int it = 0; it < 4; ++it) {   // stage [256]x[32] W chunk
                    int k = it * 64 + (tid >> 2);
                    int dp = (tid & 3) * 8;
                    float f[8];
                    load8(cbs, fc, cbW + (size_t)(kt * TK + k) * DIM + dc * DC + dp, f);
                    int base = k * WST + dp;
                    #pragma unroll
                    for (int e = 0; e < 8; ++e) Wld[base + e] = f[e];
                }
                __syncthreads();

                #pragma unroll
                for (int dd = 0; dd < DC / 4; ++dd) {
                    float av[4][4];
                    #pragma unroll
                    for (int i = 0; i < 4; ++i) {
                        int ab = (ty + 8 * i) * RST + dc * DC + dd * 4;
                        #pragma unroll
                        for (int e = 0; e < 4; ++e) av[i][e] = Rld[ab + e];
                    }
                    float bv[8][4];
                    #pragma unroll
                    for (int j = 0; j < 8; ++j) {
                        int bb = (tx + 32 * j) * WST + dd * 4;
                        #pragma unroll
                        for (int e = 0; e < 4; ++e) bv[j][e] = Wld[bb + e];
                    }
                    #pragma unroll
                    for (int i = 0; i < 4; ++i)
                        #pragma unroll
                        for (int j = 0; j < 8; ++j) {
                            float s = acc[i][j];
                            s = fmaf(av[i][0], bv[j][0], s);   // d ascending:
                            s = fmaf(av[i][1], bv[j][1], s);   // BLAS sgemm
                            s = fmaf(av[i][2], bv[j][2], s);   // sequential-k
                            s = fmaf(av[i][3], bv[j][3], s);   // FMA chain
                            acc[i][j] = s;
                        }
                }
            }
            // dist = fl(fl(r2 - 2*dot) + w2), f32; first-index ties
            #pragma unroll
            for (int j = 0; j < 8; ++j) {
                int k = kt * TK + tx + 32 * j;
                float w2k = w2c[k];
                #pragma unroll
                for (int i = 0; i < 4; ++i) {
                    float t2   = r2v[i] - 2.0f * acc[i][j];
                    float dist = t2 + w2k;
                    if (dist < bval[i] || (dist == bval[i] && k < bidx[i])) {
                        bval[i] = dist; bidx[i] = k;
                    }
                }
            }
        }
        // argmin across 32 lanes via LDS (no shuffles)
        __syncthreads();
        #pragma unroll
        for (int i = 0; i < 4; ++i) {
            int r = ty + 8 * i;
            candv[r * 33 + tx] = bval[i];
            candi[r * 33 + tx] = bidx[i];
        }
        __syncthreads();
        if (tid < TM) {
            float best = candv[tid * 33];
            int   bi   = candi[tid * 33];
            for (int t = 1; t < 32; ++t) {
                float v = candv[tid * 33 + t];
                int  ix = candi[tid * 33 + t];
                if (v < best || (v == best && ix < bi)) { best = v; bi = ix; }
            }
            bestk[tid] = bi;
            size_t pos = IDX_F + (size_t)(row0 + tid) * NCBK + cb;
            if (pos < IDXE_F) out[pos] = (float)bi;
        }
        __syncthreads();
        // straight-through dance, elementwise f32 (np bit order):
        // t = zq - r; s = r + t; r' = r - s; q += s; loss += t^2
        #pragma unroll
        for (int it = 0; it < 4; ++it) {
            int flat = it * 256 + tid;
            int r = flat >> 5, c8 = flat & 31;
            int kb = bestk[r];
            float f[8];
            load8(cbs, fc, cbW + (size_t)kb * DIM + c8 * 8, f);
            int base = r * RST + c8 * 8;
            #pragma unroll
            for (int e = 0; e < 8; ++e) {
                float rv = Rld[base + e];
                float t  = f[e] - rv;
                float s  = rv + t;
                float rn = rv - s;
                Rld[base + e] = rn;
                q[it * 8 + e] = q[it * 8 + e] + s;
                lsum += (double)t * (double)t;
            }
        }
        __syncthreads();
    }

    // quant_sum writes from registers (f32)
    #pragma unroll
    for (int it = 0; it < 4; ++it) {
        int flat = it * 256 + tid;
        int r = flat >> 5, c8 = flat & 31;
        size_t pos = (size_t)(row0 + r) * DIM + c8 * 8;
        if (pos + 8 <= QS_F) {
            #pragma unroll
            for (int e = 0; e < 8; ++e) out[pos + e] = q[it * 8 + e];
        }
    }

    // loss: per-block f64 LDS tree -> partials[block]
    dred[tid] = lsum;
    __syncthreads();
    for (int s = 128; s > 0; s >>= 1) {
        if (tid < s) dred[tid] += dred[tid + s];
        __syncthreads();
    }
    if (tid == 0) partials[blockIdx.x] = dred[0];
}

__global__ void loss_final(const double* partials, float* out) {
    __shared__ double sred[256];
    int tid = threadIdx.x;
    double s = 0.0;
    for (int q = 0; q < 8; ++q) s += partials[tid + 256 * q];
    sred[tid] = s;
    __syncthreads();
    for (int st = 128; st > 0; st >>= 1) {
        if (tid < st) sred[tid] += sred[tid + st];
        __syncthreads();
    }
    if (tid == 0)
        out[LOSS_F] = (float)(2.0 * sred[0] / 16777216.0);  // 2*S/(N*D)
}

extern "C" void kernel_launch(void* const* d_in, const int* in_sizes, int n_in,
                              void* d_out, int out_size, void* d_ws, size_t ws_size,
                              hipStream_t stream) {
    (void)n_in; (void)out_size; (void)ws_size;
    const void* z;
    const void* cbs;
    if (in_sizes[0] == 16777216) { z = d_in[0]; cbs = d_in[1]; }
    else                         { z = d_in[1]; cbs = d_in[0]; }

    float*  out      = (float*)d_out;
    float*  w2f      = (float*)d_ws;
    double* partials = (double*)((char*)d_ws + WS_PART_OFF);
    int*    flags    = (int*)((char*)d_ws + WS_FLAG_OFF);

    canary_kernel<<<1024, 256, 0, stream>>>(out);
    detect_kernel<<<1, 256, 0, stream>>>((const u16*)z, (const u16*)cbs, flags);
    w2_kernel<<<16, 256, 0, stream>>>(cbs, w2f, flags);
    rq_kernel<<<N_TOK / TM, 256, 0, stream>>>(z, cbs, w2f, out, partials, flags);
    loss_final<<<1, 256, 0, stream>>>(partials, out);
}